// Round 1
// baseline (6502.612 us; speedup 1.0000x reference)
//
#include <hip/hip_runtime.h>
#include <math.h>

#define Bb 2
#define Tt 4096
#define Cc 768
#define Hh 12
#define Dd 64

// ---------------------------------------------------------------------------
// Tiled fp32 GEMM with bias: C[M,N] = A[M,K] @ B[K,N] + bias[N]
// BM=BN=64, BK=16, 256 threads, 4x4 micro-tile per thread.
// ---------------------------------------------------------------------------
__global__ __launch_bounds__(256)
void gemm_bias(const float* __restrict__ A, const float* __restrict__ Bm,
               const float* __restrict__ bias, float* __restrict__ C,
               int M, int N, int K) {
    const int BM = 64, BN = 64, BK = 16;
    __shared__ float As[BK][BM + 4];   // padded, transposed: As[k][m]
    __shared__ float Bs[BK][BN];       // Bs[k][n]

    int tid = threadIdx.x;                 // 0..255
    int nb = blockIdx.x * BN;
    int mb = blockIdx.y * BM;
    int tx = tid & 15;                     // 0..15  (n dir)
    int ty = tid >> 4;                     // 0..15  (m dir)

    float acc[4][4] = {};

    for (int k0 = 0; k0 < K; k0 += BK) {
        // Load A tile: 64 rows x 16 cols. thread t -> row t/4, cols (t%4)*4..+3
        {
            int row = tid >> 2;
            int col = (tid & 3) * 4;
            float4 v = *(const float4*)(A + (size_t)(mb + row) * K + k0 + col);
            As[col + 0][row] = v.x;
            As[col + 1][row] = v.y;
            As[col + 2][row] = v.z;
            As[col + 3][row] = v.w;
        }
        // Load B tile: 16 rows x 64 cols. thread t -> row t/16, cols (t%16)*4..+3
        {
            int row = tid >> 4;
            int col = (tid & 15) * 4;
            *(float4*)&Bs[row][col] = *(const float4*)(Bm + (size_t)(k0 + row) * N + nb + col);
        }
        __syncthreads();

        #pragma unroll
        for (int k = 0; k < BK; ++k) {
            float4 a4 = *(const float4*)&As[k][ty * 4];
            float4 b4 = *(const float4*)&Bs[k][tx * 4];
            float a[4] = {a4.x, a4.y, a4.z, a4.w};
            float b[4] = {b4.x, b4.y, b4.z, b4.w};
            #pragma unroll
            for (int i = 0; i < 4; ++i)
                #pragma unroll
                for (int j = 0; j < 4; ++j)
                    acc[i][j] += a[i] * b[j];
        }
        __syncthreads();
    }

    float4 bv = *(const float4*)(bias + nb + tx * 4);
    #pragma unroll
    for (int i = 0; i < 4; ++i) {
        int row = mb + ty * 4 + i;
        float4 o;
        o.x = acc[i][0] + bv.x;
        o.y = acc[i][1] + bv.y;
        o.z = acc[i][2] + bv.z;
        o.w = acc[i][3] + bv.w;
        *(float4*)(C + (size_t)row * N + nb + tx * 4) = o;
    }
}

// ---------------------------------------------------------------------------
// Causal flash-style attention, fp32.
// grid: (T/64, H, B). block: 64 threads (1 wave). Thread t owns query row
// qb*64+t. K/V tiles of 64 rows staged in LDS; online softmax per thread.
// qkv layout: [B, T, 3, H, D] flattened -> row stride 3*C = 2304.
// out layout: [B, T, C] with head h at column h*64.
// ---------------------------------------------------------------------------
__global__ __launch_bounds__(64)
void attn_causal(const float* __restrict__ qkv, float* __restrict__ out) {
    int qb = blockIdx.x;
    int h  = blockIdx.y;
    int b  = blockIdx.z;
    int tid = threadIdx.x;                 // 0..63
    int q_row = qb * 64 + tid;

    const size_t rs = 3 * Cc;              // 2304 floats per token row
    const float* base = qkv + (size_t)b * Tt * rs;

    // Q row into registers
    float qreg[64];
    {
        const float* qptr = base + (size_t)q_row * rs + h * Dd;   // Q block offset 0
        #pragma unroll
        for (int d = 0; d < 64; d += 4) {
            float4 v = *(const float4*)(qptr + d);
            qreg[d] = v.x; qreg[d+1] = v.y; qreg[d+2] = v.z; qreg[d+3] = v.w;
        }
    }

    const float scale = 0.125f;            // 1/sqrt(64)
    float m = -1e30f;
    float l = 0.f;
    float acc[64] = {};

    __shared__ float Ks[64][68];           // pad 4 -> 16B-aligned rows, fewer conflicts
    __shared__ float Vs[64][68];

    for (int kb = 0; kb <= qb; ++kb) {
        // Cooperative coalesced staging: pass p loads rows p*4 + tid/16,
        // 16 lanes x float4 cover one 64-float row.
        {
            int r = tid >> 4;              // 0..3
            int col = (tid & 15) * 4;
            #pragma unroll
            for (int p = 0; p < 16; ++p) {
                int row = p * 4 + r;
                const float* kp = base + (size_t)(kb * 64 + row) * rs + Cc + h * Dd + col;
                *(float4*)&Ks[row][col] = *(const float4*)kp;
                *(float4*)&Vs[row][col] = *(const float4*)(kp + Cc);
            }
        }
        __syncthreads();

        int kmax = (kb == qb) ? (tid + 1) : 64;   // # valid keys in this tile
        #pragma unroll 1
        for (int kk0 = 0; kk0 < 64; kk0 += 16) {
            if (kk0 >= kmax) break;
            float s[16];
            float tmax = -1e30f;
            #pragma unroll
            for (int i = 0; i < 16; ++i) {
                float ds = 0.f;
                #pragma unroll
                for (int d = 0; d < 64; d += 4) {
                    float4 kv = *(const float4*)&Ks[kk0 + i][d];
                    ds += qreg[d] * kv.x + qreg[d+1] * kv.y
                        + qreg[d+2] * kv.z + qreg[d+3] * kv.w;
                }
                s[i] = (kk0 + i < kmax) ? ds * scale : -1e30f;
                tmax = fmaxf(tmax, s[i]);
            }
            float m_new = fmaxf(m, tmax);
            float corr = __expf(m - m_new);
            l *= corr;
            #pragma unroll
            for (int d = 0; d < 64; ++d) acc[d] *= corr;
            #pragma unroll
            for (int i = 0; i < 16; ++i) {
                float p = __expf(s[i] - m_new);
                l += p;
                #pragma unroll
                for (int d = 0; d < 64; d += 4) {
                    float4 vv = *(const float4*)&Vs[kk0 + i][d];
                    acc[d]   += p * vv.x;
                    acc[d+1] += p * vv.y;
                    acc[d+2] += p * vv.z;
                    acc[d+3] += p * vv.w;
                }
            }
            m = m_new;
        }
        __syncthreads();
    }

    float inv_l = 1.f / l;
    float* optr = out + ((size_t)b * Tt + q_row) * Cc + h * Dd;
    #pragma unroll
    for (int d = 0; d < 64; d += 4) {
        float4 v;
        v.x = acc[d]   * inv_l;
        v.y = acc[d+1] * inv_l;
        v.z = acc[d+2] * inv_l;
        v.w = acc[d+3] * inv_l;
        *(float4*)(optr + d) = v;
    }
}

// ---------------------------------------------------------------------------
extern "C" void kernel_launch(void* const* d_in, const int* in_sizes, int n_in,
                              void* d_out, int out_size, void* d_ws, size_t ws_size,
                              hipStream_t stream) {
    const float* x    = (const float*)d_in[0];   // [2,4096,768]
    const float* Wqkv = (const float*)d_in[1];   // [768,2304]
    const float* bqkv = (const float*)d_in[2];   // [2304]
    const float* Wout = (const float*)d_in[3];   // [768,768]
    const float* bout = (const float*)d_in[4];   // [768]
    float* out = (float*)d_out;                  // [2,4096,768]

    float* qkv      = (float*)d_ws;                        // 8192*2304 floats (75.5 MB)
    float* attn_out = qkv + (size_t)(Bb * Tt) * (3 * Cc);  // 8192*768 floats (25.2 MB)

    const int M = Bb * Tt;     // 8192

    // 1) qkv = x @ Wqkv + bqkv
    gemm_bias<<<dim3((3 * Cc) / 64, M / 64), dim3(256), 0, stream>>>(
        x, Wqkv, bqkv, qkv, M, 3 * Cc, Cc);

    // 2) causal attention, per-head, writes [B,T,C] (head-interleaved)
    attn_causal<<<dim3(Tt / 64, Hh, Bb), dim3(64), 0, stream>>>(qkv, attn_out);

    // 3) out = attn_out @ Wout + bout
    gemm_bias<<<dim3(Cc / 64, M / 64), dim3(256), 0, stream>>>(
        attn_out, Wout, bout, out, M, Cc, Cc);
}

// Round 2
// 892.064 us; speedup vs baseline: 7.2894x; 7.2894x over previous
//
#include <hip/hip_runtime.h>
#include <math.h>

#define Bb 2
#define Tt 4096
#define Cc 768
#define Hh 12
#define Dd 64

typedef __attribute__((ext_vector_type(8))) short short8;
typedef __attribute__((ext_vector_type(4))) float f32x4;

static __device__ __forceinline__ unsigned short f2bf(float f) {
    unsigned u = __float_as_uint(f);
    u += 0x7FFF + ((u >> 16) & 1);          // round-to-nearest-even
    return (unsigned short)(u >> 16);
}

// ---------------------------------------------------------------------------
// Tiled fp32 GEMM with bias: C[M,N] = A[M,K] @ B[K,N] + bias[N]
// ---------------------------------------------------------------------------
__global__ __launch_bounds__(256)
void gemm_bias(const float* __restrict__ A, const float* __restrict__ Bm,
               const float* __restrict__ bias, float* __restrict__ C,
               int M, int N, int K) {
    const int BK = 16;
    __shared__ float As[BK][64 + 4];
    __shared__ float Bs[BK][64];

    int tid = threadIdx.x;
    int nb = blockIdx.x * 64;
    int mb = blockIdx.y * 64;
    int tx = tid & 15;
    int ty = tid >> 4;

    float acc[4][4] = {};

    for (int k0 = 0; k0 < K; k0 += BK) {
        {
            int row = tid >> 2;
            int col = (tid & 3) * 4;
            float4 v = *(const float4*)(A + (size_t)(mb + row) * K + k0 + col);
            As[col + 0][row] = v.x;
            As[col + 1][row] = v.y;
            As[col + 2][row] = v.z;
            As[col + 3][row] = v.w;
        }
        {
            int row = tid >> 4;
            int col = (tid & 15) * 4;
            *(float4*)&Bs[row][col] = *(const float4*)(Bm + (size_t)(k0 + row) * N + nb + col);
        }
        __syncthreads();

        #pragma unroll
        for (int k = 0; k < BK; ++k) {
            float4 a4 = *(const float4*)&As[k][ty * 4];
            float4 b4 = *(const float4*)&Bs[k][tx * 4];
            float a[4] = {a4.x, a4.y, a4.z, a4.w};
            float b[4] = {b4.x, b4.y, b4.z, b4.w};
            #pragma unroll
            for (int i = 0; i < 4; ++i)
                #pragma unroll
                for (int j = 0; j < 4; ++j)
                    acc[i][j] += a[i] * b[j];
        }
        __syncthreads();
    }

    float4 bv = *(const float4*)(bias + nb + tx * 4);
    #pragma unroll
    for (int i = 0; i < 4; ++i) {
        int row = mb + ty * 4 + i;
        float4 o;
        o.x = acc[i][0] + bv.x;
        o.y = acc[i][1] + bv.y;
        o.z = acc[i][2] + bv.z;
        o.w = acc[i][3] + bv.w;
        *(float4*)(C + (size_t)row * N + nb + tx * 4) = o;
    }
}

// ---------------------------------------------------------------------------
// Flash attention, bf16 MFMA (16x16x32). Block = 256 threads = 4 waves.
// Block handles 64 q-rows of one (b,h); wave w owns q-strip [w*16, w*16+16).
// qkv fp32 [B,T,3,H,D] (row stride 2304). out fp32 [B,T,C].
//
// mfma_f32_16x16x32_bf16 layouts (m89-verified):
//   A: lane l -> row l&15,           k = (l>>4)*8 + j   (j=0..7)
//   B: lane l -> col l&15,           k = (l>>4)*8 + j
//   C/D: lane l -> col l&15, row = (l>>4)*4 + r         (r=0..3)
// ---------------------------------------------------------------------------
__global__ __launch_bounds__(256)
void attn_mfma(const float* __restrict__ qkv, float* __restrict__ out) {
    const int qb = blockIdx.x;
    const int h  = blockIdx.y;
    const int b  = blockIdx.z;
    const int tid = threadIdx.x;
    const int wid = tid >> 6;
    const int lane = tid & 63;
    const int lr = lane & 15;
    const int g  = lane >> 4;
    const int q0 = qb * 64;
    const size_t rs = 3 * Cc;   // 2304

    __shared__ unsigned short Ks[64][72];        // K  [key][d]
    __shared__ unsigned short Vt[64][72];        // V^T [d][key]
    __shared__ unsigned short Ps[4][16][72];     // per-wave P [q][key]

    const float* base = qkv + (size_t)b * Tt * rs;

    // ---- Q A-fragments (scale folded in) ----
    short8 qf[2];
    {
        const float* qptr = base + (size_t)(q0 + wid * 16 + lr) * rs + h * Dd;
        #pragma unroll
        for (int s = 0; s < 2; ++s)
            #pragma unroll
            for (int j = 0; j < 8; ++j)
                qf[s][j] = (short)f2bf(qptr[s * 32 + g * 8 + j] * 0.125f);
    }

    f32x4 o_acc[4];
    #pragma unroll
    for (int dt = 0; dt < 4; ++dt) o_acc[dt] = (f32x4){0.f, 0.f, 0.f, 0.f};
    float m_r[4] = {-1e30f, -1e30f, -1e30f, -1e30f};
    float l_r[4] = {0.f, 0.f, 0.f, 0.f};

    const int r_st = tid >> 2;          // staging row 0..63
    const int c0   = (tid & 3) * 16;    // staging col base

    for (int kbt = 0; kbt <= qb; ++kbt) {
        // ---- stage K (row-major) and V (transposed) into LDS, fp32->bf16 ----
        {
            const float* kp = base + (size_t)(kbt * 64 + r_st) * rs + Cc + h * Dd + c0;
            float4 k0 = *(const float4*)(kp + 0);
            float4 k1 = *(const float4*)(kp + 4);
            float4 k2 = *(const float4*)(kp + 8);
            float4 k3 = *(const float4*)(kp + 12);
            union { short8 v; unsigned short u[8]; } p0, p1;
            p0.u[0] = f2bf(k0.x); p0.u[1] = f2bf(k0.y); p0.u[2] = f2bf(k0.z); p0.u[3] = f2bf(k0.w);
            p0.u[4] = f2bf(k1.x); p0.u[5] = f2bf(k1.y); p0.u[6] = f2bf(k1.z); p0.u[7] = f2bf(k1.w);
            p1.u[0] = f2bf(k2.x); p1.u[1] = f2bf(k2.y); p1.u[2] = f2bf(k2.z); p1.u[3] = f2bf(k2.w);
            p1.u[4] = f2bf(k3.x); p1.u[5] = f2bf(k3.y); p1.u[6] = f2bf(k3.z); p1.u[7] = f2bf(k3.w);
            *(short8*)&Ks[r_st][c0]     = p0.v;
            *(short8*)&Ks[r_st][c0 + 8] = p1.v;

            const float* vp = kp + Cc;
            float4 v0 = *(const float4*)(vp + 0);
            float4 v1 = *(const float4*)(vp + 4);
            float4 v2 = *(const float4*)(vp + 8);
            float4 v3 = *(const float4*)(vp + 12);
            float vv[16] = {v0.x, v0.y, v0.z, v0.w, v1.x, v1.y, v1.z, v1.w,
                            v2.x, v2.y, v2.z, v2.w, v3.x, v3.y, v3.z, v3.w};
            #pragma unroll
            for (int j = 0; j < 16; ++j)
                Vt[c0 + j][r_st] = f2bf(vv[j]);
        }
        __syncthreads();

        // ---- S = Q K^T strip (16q x 64k per wave) ----
        f32x4 st[4];
        #pragma unroll
        for (int kt = 0; kt < 4; ++kt) {
            short8 kf0 = *(const short8*)&Ks[kt * 16 + lr][g * 8];
            short8 kf1 = *(const short8*)&Ks[kt * 16 + lr][32 + g * 8];
            f32x4 acc = (f32x4){0.f, 0.f, 0.f, 0.f};
            acc = __builtin_amdgcn_mfma_f32_16x16x32_bf16(qf[0], kf0, acc, 0, 0, 0);
            acc = __builtin_amdgcn_mfma_f32_16x16x32_bf16(qf[1], kf1, acc, 0, 0, 0);
            st[kt] = acc;
        }

        // ---- causal mask on the diagonal block ----
        if (kbt == qb) {
            #pragma unroll
            for (int kt = 0; kt < 4; ++kt)
                #pragma unroll
                for (int r = 0; r < 4; ++r)
                    if (kt * 16 + lr > wid * 16 + g * 4 + r) st[kt][r] = -1e30f;
        }

        // ---- online softmax (row reduce over 16 lanes sharing g) ----
        float tmax[4], psum[4], mnew[4], corr[4];
        #pragma unroll
        for (int r = 0; r < 4; ++r)
            tmax[r] = fmaxf(fmaxf(st[0][r], st[1][r]), fmaxf(st[2][r], st[3][r]));
        #pragma unroll
        for (int off = 1; off < 16; off <<= 1)
            #pragma unroll
            for (int r = 0; r < 4; ++r)
                tmax[r] = fmaxf(tmax[r], __shfl_xor(tmax[r], off));
        #pragma unroll
        for (int r = 0; r < 4; ++r) {
            mnew[r] = fmaxf(m_r[r], tmax[r]);
            corr[r] = __expf(m_r[r] - mnew[r]);
            psum[r] = 0.f;
        }
        #pragma unroll
        for (int kt = 0; kt < 4; ++kt)
            #pragma unroll
            for (int r = 0; r < 4; ++r) {
                float p = __expf(st[kt][r] - mnew[r]);
                st[kt][r] = p;
                psum[r] += p;
            }
        #pragma unroll
        for (int off = 1; off < 16; off <<= 1)
            #pragma unroll
            for (int r = 0; r < 4; ++r)
                psum[r] += __shfl_xor(psum[r], off);
        #pragma unroll
        for (int r = 0; r < 4; ++r) {
            l_r[r] = l_r[r] * corr[r] + psum[r];
            m_r[r] = mnew[r];
        }
        #pragma unroll
        for (int dt = 0; dt < 4; ++dt)
            #pragma unroll
            for (int r = 0; r < 4; ++r)
                o_acc[dt][r] *= corr[r];

        // ---- P (C-layout) -> LDS -> A-layout for PV ----
        #pragma unroll
        for (int kt = 0; kt < 4; ++kt)
            #pragma unroll
            for (int r = 0; r < 4; ++r)
                Ps[wid][g * 4 + r][kt * 16 + lr] = f2bf(st[kt][r]);
        asm volatile("s_waitcnt lgkmcnt(0)" ::: "memory");

        #pragma unroll
        for (int ks = 0; ks < 2; ++ks) {
            short8 pa = *(const short8*)&Ps[wid][lr][ks * 32 + g * 8];
            #pragma unroll
            for (int dt = 0; dt < 4; ++dt) {
                short8 vf = *(const short8*)&Vt[dt * 16 + lr][ks * 32 + g * 8];
                o_acc[dt] = __builtin_amdgcn_mfma_f32_16x16x32_bf16(pa, vf, o_acc[dt], 0, 0, 0);
            }
        }
        __syncthreads();
    }

    // ---- epilogue ----
    float inv[4];
    #pragma unroll
    for (int r = 0; r < 4; ++r) inv[r] = 1.f / l_r[r];
    #pragma unroll
    for (int dt = 0; dt < 4; ++dt)
        #pragma unroll
        for (int r = 0; r < 4; ++r) {
            int q = q0 + wid * 16 + g * 4 + r;
            out[((size_t)b * Tt + q) * Cc + h * Dd + dt * 16 + lr] = o_acc[dt][r] * inv[r];
        }
}

// ---------------------------------------------------------------------------
extern "C" void kernel_launch(void* const* d_in, const int* in_sizes, int n_in,
                              void* d_out, int out_size, void* d_ws, size_t ws_size,
                              hipStream_t stream) {
    const float* x    = (const float*)d_in[0];
    const float* Wqkv = (const float*)d_in[1];
    const float* bqkv = (const float*)d_in[2];
    const float* Wout = (const float*)d_in[3];
    const float* bout = (const float*)d_in[4];
    float* out = (float*)d_out;

    float* qkv      = (float*)d_ws;                        // [8192, 2304] fp32
    float* attn_out = qkv + (size_t)(Bb * Tt) * (3 * Cc);  // [8192, 768] fp32

    const int M = Bb * Tt;  // 8192

    gemm_bias<<<dim3((3 * Cc) / 64, M / 64), dim3(256), 0, stream>>>(
        x, Wqkv, bqkv, qkv, M, 3 * Cc, Cc);

    attn_mfma<<<dim3(Tt / 64, Hh, Bb), dim3(256), 0, stream>>>(qkv, attn_out);

    gemm_bias<<<dim3(Cc / 64, M / 64), dim3(256), 0, stream>>>(
        attn_out, Wout, bout, out, M, Cc, Cc);
}

// Round 3
// 440.043 us; speedup vs baseline: 14.7772x; 2.0272x over previous
//
#include <hip/hip_runtime.h>
#include <math.h>

#define Bb 2
#define Tt 4096
#define Cc 768
#define Hh 12
#define Dd 64

typedef __attribute__((ext_vector_type(8))) short short8;
typedef __attribute__((ext_vector_type(4))) float f32x4;

static __device__ __forceinline__ unsigned short f2bf(float f) {
    unsigned u = __float_as_uint(f);
    u += 0x7FFF + ((u >> 16) & 1);          // round-to-nearest-even
    return (unsigned short)(u >> 16);
}

static __device__ __forceinline__ void gload16(const void* g, void* l) {
    __builtin_amdgcn_global_load_lds(
        (const __attribute__((address_space(1))) unsigned*)g,
        (__attribute__((address_space(3))) unsigned*)l, 16, 0, 0);
}

// ---------------------------------------------------------------------------
// fp32 -> bf16 elementwise convert (8 elems/thread)
// ---------------------------------------------------------------------------
__global__ __launch_bounds__(256)
void cvt_bf16(const float* __restrict__ in, unsigned short* __restrict__ out, int n8) {
    int i = blockIdx.x * 256 + threadIdx.x;
    if (i >= n8) return;
    float4 a = *(const float4*)(in + (size_t)i * 8);
    float4 b = *(const float4*)(in + (size_t)i * 8 + 4);
    union { short8 v; unsigned short u[8]; } p;
    p.u[0] = f2bf(a.x); p.u[1] = f2bf(a.y); p.u[2] = f2bf(a.z); p.u[3] = f2bf(a.w);
    p.u[4] = f2bf(b.x); p.u[5] = f2bf(b.y); p.u[6] = f2bf(b.z); p.u[7] = f2bf(b.w);
    *(short8*)(out + (size_t)i * 8) = p.v;
}

// ---------------------------------------------------------------------------
// W[K][N] fp32 -> Wt[N][K] bf16 (64x64 LDS tile transpose)
// grid: (N/64, K/64)
// ---------------------------------------------------------------------------
__global__ __launch_bounds__(256)
void transpose_w(const float* __restrict__ W, unsigned short* __restrict__ Wt,
                 int K, int N) {
    __shared__ __align__(16) unsigned short Tl[64][72];
    int n0 = blockIdx.x * 64, k0 = blockIdx.y * 64;
    int t = threadIdx.x;
    int r = t >> 2, c = (t & 3) * 16;
    const float* wp = W + (size_t)(k0 + r) * N + n0 + c;
    #pragma unroll
    for (int j = 0; j < 16; j += 4) {
        float4 v = *(const float4*)(wp + j);
        Tl[c + j + 0][r] = f2bf(v.x);
        Tl[c + j + 1][r] = f2bf(v.y);
        Tl[c + j + 2][r] = f2bf(v.z);
        Tl[c + j + 3][r] = f2bf(v.w);
    }
    __syncthreads();
    unsigned short* op = Wt + (size_t)(n0 + r) * K + k0 + c;
    *(short8*)op       = *(const short8*)&Tl[r][c];
    *(short8*)(op + 8) = *(const short8*)&Tl[r][c + 8];
}

// ---------------------------------------------------------------------------
// V slice of bf16 qkv -> Vt[b][h][d][t]  (64x64 LDS tile transpose)
// grid: (T/64, H, B)
// ---------------------------------------------------------------------------
__global__ __launch_bounds__(256)
void repack_vt(const unsigned short* __restrict__ qkvb, unsigned short* __restrict__ vtb) {
    __shared__ __align__(16) unsigned short Tl[64][72];
    int t0 = blockIdx.x * 64, h = blockIdx.y, b = blockIdx.z;
    int t = threadIdx.x;
    int r = t >> 2, c = (t & 3) * 16;
    const unsigned short* vp = qkvb + (size_t)((size_t)b * Tt + t0 + r) * (3 * Cc)
                               + 2 * Cc + h * Dd + c;
    short8 v0 = *(const short8*)vp;
    short8 v1 = *(const short8*)(vp + 8);
    #pragma unroll
    for (int j = 0; j < 8; ++j) {
        Tl[c + j][r]     = ((unsigned short*)&v0)[j];
        Tl[c + 8 + j][r] = ((unsigned short*)&v1)[j];
    }
    __syncthreads();
    unsigned short* op = vtb + ((size_t)((b * Hh + h) * Dd) + r) * Tt + t0 + c;
    *(short8*)op       = *(const short8*)&Tl[r][c];
    *(short8*)(op + 8) = *(const short8*)&Tl[r][c + 8];
}

// ---------------------------------------------------------------------------
// bf16 MFMA GEMM: C[M,N] = A[M,K] @ Bt[N,K]^T + bias.
// 128x128 tile, BK=64, 256 threads (4 waves, 2x2), global_load_lds staging.
// BF16OUT: write bf16 (qkv) else fp32 (final out).
// ---------------------------------------------------------------------------
template<bool BF16OUT>
__global__ __launch_bounds__(256)
void gemm_mfma(const unsigned short* __restrict__ A, const unsigned short* __restrict__ Bt,
               const float* __restrict__ bias, void* __restrict__ Cout,
               int M, int N, int K) {
    __shared__ __align__(16) unsigned short As[128][64];
    __shared__ __align__(16) unsigned short Bs[128][64];
    const int tid = threadIdx.x;
    const int wid = tid >> 6, lane = tid & 63;
    const int lr = lane & 15, g = lane >> 4;
    const int wr = wid >> 1, wc = wid & 1;
    const int m0 = blockIdx.y * 128, n0 = blockIdx.x * 128;
    const int srow = lane >> 3;            // 0..7 row within 8-row chunk
    const int scol = (lane & 7) * 8;       // short col

    f32x4 acc[4][4] = {};

    for (int k0 = 0; k0 < K; k0 += 64) {
        #pragma unroll
        for (int j = 0; j < 4; ++j) {
            int ci = wid * 4 + j;
            int row = ci * 8 + srow;
            gload16(A  + (size_t)(m0 + row) * K + k0 + scol, &As[ci * 8][0]);
            gload16(Bt + (size_t)(n0 + row) * K + k0 + scol, &Bs[ci * 8][0]);
        }
        __syncthreads();
        #pragma unroll
        for (int ks = 0; ks < 2; ++ks) {
            short8 af[4], bfr[4];
            #pragma unroll
            for (int m = 0; m < 4; ++m)
                af[m] = *(const short8*)&As[wr * 64 + m * 16 + lr][ks * 32 + g * 8];
            #pragma unroll
            for (int n = 0; n < 4; ++n)
                bfr[n] = *(const short8*)&Bs[wc * 64 + n * 16 + lr][ks * 32 + g * 8];
            #pragma unroll
            for (int m = 0; m < 4; ++m)
                #pragma unroll
                for (int n = 0; n < 4; ++n)
                    acc[m][n] = __builtin_amdgcn_mfma_f32_16x16x32_bf16(
                        af[m], bfr[n], acc[m][n], 0, 0, 0);
        }
        __syncthreads();
    }

    #pragma unroll
    for (int n = 0; n < 4; ++n) {
        int coln = n0 + wc * 64 + n * 16 + lr;
        float bv = bias[coln];
        #pragma unroll
        for (int m = 0; m < 4; ++m) {
            int rowb = m0 + wr * 64 + m * 16 + g * 4;
            #pragma unroll
            for (int r = 0; r < 4; ++r) {
                float v = acc[m][n][r] + bv;
                if (BF16OUT)
                    ((unsigned short*)Cout)[(size_t)(rowb + r) * N + coln] = f2bf(v);
                else
                    ((float*)Cout)[(size_t)(rowb + r) * N + coln] = v;
            }
        }
    }
}

// ---------------------------------------------------------------------------
// Flash attention, bf16 in/out. 512 threads = 8 waves; block owns 128 q-rows
// of one (b,h); wave w owns q-strip [w*16, w*16+16). KV tile = 64.
// qkvb bf16 [B*T][2304]; vtb bf16 [B][H][D][T]; outb bf16 [B*T][768].
// ---------------------------------------------------------------------------
__global__ __launch_bounds__(512)
void attn_mfma(const unsigned short* __restrict__ qkvb,
               const unsigned short* __restrict__ vtb,
               unsigned short* __restrict__ outb) {
    const int qb = blockIdx.x;
    const int h  = blockIdx.y;
    const int b  = blockIdx.z;
    const int tid = threadIdx.x;
    const int wid = tid >> 6, lane = tid & 63;
    const int lr = lane & 15, g = lane >> 4;
    const int q0 = qb * 128;
    const size_t rs = 3 * Cc;

    __shared__ __align__(16) unsigned short Ks[64][72];   // K [key][d]
    __shared__ __align__(16) unsigned short Vs[64][72];   // V^T [d][key]
    __shared__ __align__(16) unsigned short Ps[8][16][72];

    const unsigned short* qkvbase = qkvb + (size_t)b * Tt * rs;
    const unsigned short* vbase   = vtb + (size_t)((b * Hh + h) * Dd) * Tt;

    short8 qf[2];
    {
        const unsigned short* qptr = qkvbase + (size_t)(q0 + wid * 16 + lr) * rs + h * Dd;
        qf[0] = *(const short8*)(qptr + g * 8);
        qf[1] = *(const short8*)(qptr + 32 + g * 8);
    }

    f32x4 o_acc[4];
    #pragma unroll
    for (int dt = 0; dt < 4; ++dt) o_acc[dt] = (f32x4){0.f, 0.f, 0.f, 0.f};
    float m_r[4] = {-1e30f, -1e30f, -1e30f, -1e30f};
    float l_r[4] = {0.f, 0.f, 0.f, 0.f};

    const int strow = tid >> 3;         // 0..63
    const int stcol = (tid & 7) * 8;
    const int ntiles = 2 * qb + 2;
    const int mymax = q0 + wid * 16 + 15;   // max q-row this wave owns

    for (int kbt = 0; kbt < ntiles; ++kbt) {
        {
            const unsigned short* kp = qkvbase + (size_t)(kbt * 64 + strow) * rs
                                       + Cc + h * Dd + stcol;
            *(short8*)&Ks[strow][stcol] = *(const short8*)kp;
            const unsigned short* vp = vbase + (size_t)strow * Tt + kbt * 64 + stcol;
            *(short8*)&Vs[strow][stcol] = *(const short8*)vp;
        }
        __syncthreads();

        if (kbt * 64 <= mymax) {
            // ---- S = Q K^T ----
            f32x4 st[4];
            #pragma unroll
            for (int kt = 0; kt < 4; ++kt) {
                short8 kf0 = *(const short8*)&Ks[kt * 16 + lr][g * 8];
                short8 kf1 = *(const short8*)&Ks[kt * 16 + lr][32 + g * 8];
                f32x4 a = (f32x4){0.f, 0.f, 0.f, 0.f};
                a = __builtin_amdgcn_mfma_f32_16x16x32_bf16(qf[0], kf0, a, 0, 0, 0);
                a = __builtin_amdgcn_mfma_f32_16x16x32_bf16(qf[1], kf1, a, 0, 0, 0);
                st[kt] = a;
            }
            #pragma unroll
            for (int kt = 0; kt < 4; ++kt)
                #pragma unroll
                for (int r = 0; r < 4; ++r)
                    st[kt][r] *= 0.125f;

            if (kbt * 64 + 63 > q0 + wid * 16) {   // diagonal: causal mask
                #pragma unroll
                for (int kt = 0; kt < 4; ++kt)
                    #pragma unroll
                    for (int r = 0; r < 4; ++r)
                        if (kbt * 64 + kt * 16 + lr > q0 + wid * 16 + g * 4 + r)
                            st[kt][r] = -1e30f;
            }

            // ---- online softmax (rows live across 16 lanes sharing g) ----
            float tmax[4], psum[4], mnew[4], corr[4];
            #pragma unroll
            for (int r = 0; r < 4; ++r)
                tmax[r] = fmaxf(fmaxf(st[0][r], st[1][r]), fmaxf(st[2][r], st[3][r]));
            #pragma unroll
            for (int off = 1; off < 16; off <<= 1)
                #pragma unroll
                for (int r = 0; r < 4; ++r)
                    tmax[r] = fmaxf(tmax[r], __shfl_xor(tmax[r], off));
            #pragma unroll
            for (int r = 0; r < 4; ++r) {
                mnew[r] = fmaxf(m_r[r], tmax[r]);
                corr[r] = __expf(m_r[r] - mnew[r]);
                psum[r] = 0.f;
            }
            #pragma unroll
            for (int kt = 0; kt < 4; ++kt)
                #pragma unroll
                for (int r = 0; r < 4; ++r) {
                    float p = __expf(st[kt][r] - mnew[r]);
                    st[kt][r] = p;
                    psum[r] += p;
                }
            #pragma unroll
            for (int off = 1; off < 16; off <<= 1)
                #pragma unroll
                for (int r = 0; r < 4; ++r)
                    psum[r] += __shfl_xor(psum[r], off);
            #pragma unroll
            for (int r = 0; r < 4; ++r) {
                l_r[r] = l_r[r] * corr[r] + psum[r];
                m_r[r] = mnew[r];
            }
            #pragma unroll
            for (int dt = 0; dt < 4; ++dt)
                #pragma unroll
                for (int r = 0; r < 4; ++r)
                    o_acc[dt][r] *= corr[r];

            // ---- P (C-layout) -> per-wave LDS strip -> A-layout ----
            #pragma unroll
            for (int kt = 0; kt < 4; ++kt)
                #pragma unroll
                for (int r = 0; r < 4; ++r)
                    Ps[wid][g * 4 + r][kt * 16 + lr] = f2bf(st[kt][r]);
            asm volatile("s_waitcnt lgkmcnt(0)" ::: "memory");
            __builtin_amdgcn_sched_barrier(0);

            #pragma unroll
            for (int ks = 0; ks < 2; ++ks) {
                short8 pa = *(const short8*)&Ps[wid][lr][ks * 32 + g * 8];
                #pragma unroll
                for (int dt = 0; dt < 4; ++dt) {
                    short8 vf = *(const short8*)&Vs[dt * 16 + lr][ks * 32 + g * 8];
                    o_acc[dt] = __builtin_amdgcn_mfma_f32_16x16x32_bf16(
                        pa, vf, o_acc[dt], 0, 0, 0);
                }
            }
        }
        __syncthreads();
    }

    float inv[4];
    #pragma unroll
    for (int r = 0; r < 4; ++r) inv[r] = 1.f / l_r[r];
    #pragma unroll
    for (int dt = 0; dt < 4; ++dt)
        #pragma unroll
        for (int r = 0; r < 4; ++r) {
            int q = q0 + wid * 16 + g * 4 + r;
            outb[((size_t)b * Tt + q) * Cc + h * Dd + dt * 16 + lr] =
                f2bf(o_acc[dt][r] * inv[r]);
        }
}

// ---------------------------------------------------------------------------
extern "C" void kernel_launch(void* const* d_in, const int* in_sizes, int n_in,
                              void* d_out, int out_size, void* d_ws, size_t ws_size,
                              hipStream_t stream) {
    const float* x    = (const float*)d_in[0];
    const float* Wqkv = (const float*)d_in[1];
    const float* bqkv = (const float*)d_in[2];
    const float* Wout = (const float*)d_in[3];
    const float* bout = (const float*)d_in[4];
    float* out = (float*)d_out;

    const int M = Bb * Tt;          // 8192
    const int N1 = 3 * Cc;          // 2304

    char* p = (char*)d_ws;
    unsigned short* qkvb  = (unsigned short*)p; p += (size_t)M * N1 * 2;        // 37.7 MB
    unsigned short* xb    = (unsigned short*)p; p += (size_t)M * Cc * 2;        // 12.6 MB
    unsigned short* wqkvt = (unsigned short*)p; p += (size_t)N1 * Cc * 2;       //  3.5 MB
    unsigned short* woutt = (unsigned short*)p; p += (size_t)Cc * Cc * 2;       //  1.2 MB
    unsigned short* vtb   = (unsigned short*)p; p += (size_t)Bb * Hh * Dd * Tt * 2; // 12.6 MB
    unsigned short* attb  = (unsigned short*)p; p += (size_t)M * Cc * 2;        // 12.6 MB

    // 1) convert inputs to bf16 (x) and transposed bf16 (weights)
    cvt_bf16<<<dim3((M * Cc / 8 + 255) / 256), dim3(256), 0, stream>>>(x, xb, M * Cc / 8);
    transpose_w<<<dim3(N1 / 64, Cc / 64), dim3(256), 0, stream>>>(Wqkv, wqkvt, Cc, N1);
    transpose_w<<<dim3(Cc / 64, Cc / 64), dim3(256), 0, stream>>>(Wout, woutt, Cc, Cc);

    // 2) qkv = x @ Wqkv + bqkv   (bf16 out)
    gemm_mfma<true><<<dim3(N1 / 128, M / 128), dim3(256), 0, stream>>>(
        xb, wqkvt, bqkv, qkvb, M, N1, Cc);

    // 3) repack V transposed per head
    repack_vt<<<dim3(Tt / 64, Hh, Bb), dim3(256), 0, stream>>>(qkvb, vtb);

    // 4) causal flash attention (bf16 out)
    attn_mfma<<<dim3(Tt / 128, Hh, Bb), dim3(512), 0, stream>>>(qkvb, vtb, attb);

    // 5) out = attn @ Wout + bout  (fp32 out)
    gemm_mfma<false><<<dim3(Cc / 128, M / 128), dim3(256), 0, stream>>>(
        attb, woutt, bout, out, M, Cc, Cc);
}

// Round 5
// 282.928 us; speedup vs baseline: 22.9833x; 1.5553x over previous
//
#include <hip/hip_runtime.h>
#include <math.h>

#define Bb 2
#define Tt 4096
#define Cc 768
#define Hh 12
#define Dd 64

typedef __attribute__((ext_vector_type(8))) short short8;
typedef __attribute__((ext_vector_type(4))) float f32x4;
typedef __attribute__((ext_vector_type(4))) unsigned short u16x4;

static __device__ __forceinline__ unsigned short f2bf(float f) {
    unsigned u = __float_as_uint(f);
    u += 0x7FFF + ((u >> 16) & 1);          // round-to-nearest-even
    return (unsigned short)(u >> 16);
}

static __device__ __forceinline__ void gload16(const void* g, void* l) {
    __builtin_amdgcn_global_load_lds(
        (const __attribute__((address_space(1))) unsigned*)g,
        (__attribute__((address_space(3))) unsigned*)l, 16, 0, 0);
}

// ---------------------------------------------------------------------------
// fp32 -> bf16 elementwise convert (8 elems/thread)
// ---------------------------------------------------------------------------
__global__ __launch_bounds__(256)
void cvt_bf16(const float* __restrict__ in, unsigned short* __restrict__ out, int n8) {
    int i = blockIdx.x * 256 + threadIdx.x;
    if (i >= n8) return;
    float4 a = *(const float4*)(in + (size_t)i * 8);
    float4 b = *(const float4*)(in + (size_t)i * 8 + 4);
    union { short8 v; unsigned short u[8]; } p;
    p.u[0] = f2bf(a.x); p.u[1] = f2bf(a.y); p.u[2] = f2bf(a.z); p.u[3] = f2bf(a.w);
    p.u[4] = f2bf(b.x); p.u[5] = f2bf(b.y); p.u[6] = f2bf(b.z); p.u[7] = f2bf(b.w);
    *(short8*)(out + (size_t)i * 8) = p.v;
}

// ---------------------------------------------------------------------------
// W[K][N] fp32 -> Wt[N][K] bf16 (64x64 LDS tile transpose)
// ---------------------------------------------------------------------------
__global__ __launch_bounds__(256)
void transpose_w(const float* __restrict__ W, unsigned short* __restrict__ Wt,
                 int K, int N) {
    __shared__ __align__(16) unsigned short Tl[64][72];
    int n0 = blockIdx.x * 64, k0 = blockIdx.y * 64;
    int t = threadIdx.x;
    int r = t >> 2, c = (t & 3) * 16;
    const float* wp = W + (size_t)(k0 + r) * N + n0 + c;
    #pragma unroll
    for (int j = 0; j < 16; j += 4) {
        float4 v = *(const float4*)(wp + j);
        Tl[c + j + 0][r] = f2bf(v.x);
        Tl[c + j + 1][r] = f2bf(v.y);
        Tl[c + j + 2][r] = f2bf(v.z);
        Tl[c + j + 3][r] = f2bf(v.w);
    }
    __syncthreads();
    unsigned short* op = Wt + (size_t)(n0 + r) * K + k0 + c;
    *(short8*)op       = *(const short8*)&Tl[r][c];
    *(short8*)(op + 8) = *(const short8*)&Tl[r][c + 8];
}

// ---------------------------------------------------------------------------
// V slice of bf16 qkv -> Vt[b][h][d][t]  (64x64 LDS tile transpose)
// ---------------------------------------------------------------------------
__global__ __launch_bounds__(256)
void repack_vt(const unsigned short* __restrict__ qkvb, unsigned short* __restrict__ vtb) {
    __shared__ __align__(16) unsigned short Tl[64][72];
    int t0 = blockIdx.x * 64, h = blockIdx.y, b = blockIdx.z;
    int t = threadIdx.x;
    int r = t >> 2, c = (t & 3) * 16;
    const unsigned short* vp = qkvb + (size_t)((size_t)b * Tt + t0 + r) * (3 * Cc)
                               + 2 * Cc + h * Dd + c;
    short8 v0 = *(const short8*)vp;
    short8 v1 = *(const short8*)(vp + 8);
    #pragma unroll
    for (int j = 0; j < 8; ++j) {
        Tl[c + j][r]     = ((unsigned short*)&v0)[j];
        Tl[c + 8 + j][r] = ((unsigned short*)&v1)[j];
    }
    __syncthreads();
    unsigned short* op = vtb + ((size_t)((b * Hh + h) * Dd) + r) * Tt + t0 + c;
    *(short8*)op       = *(const short8*)&Tl[r][c];
    *(short8*)(op + 8) = *(const short8*)&Tl[r][c + 8];
}

// ---------------------------------------------------------------------------
// bf16 MFMA GEMM: C[M,N] = (A[M,K] @ Bt[N,K]^T + bias) * (col<qcols ? 0.125 : 1)
// 128x128 tile, BK=64, 256 threads (4 waves, 2x2), global_load_lds staging.
// ---------------------------------------------------------------------------
template<bool BF16OUT>
__global__ __launch_bounds__(256)
void gemm_mfma(const unsigned short* __restrict__ A, const unsigned short* __restrict__ Bt,
               const float* __restrict__ bias, void* __restrict__ Cout,
               int M, int N, int K, int qcols) {
    __shared__ __align__(16) unsigned short As[128][64];
    __shared__ __align__(16) unsigned short Bs[128][64];
    const int tid = threadIdx.x;
    const int wid = tid >> 6, lane = tid & 63;
    const int lr = lane & 15, g = lane >> 4;
    const int wr = wid >> 1, wc = wid & 1;
    const int m0 = blockIdx.y * 128, n0 = blockIdx.x * 128;
    const int srow = lane >> 3;
    const int scol = (lane & 7) * 8;

    f32x4 acc[4][4] = {};

    for (int k0 = 0; k0 < K; k0 += 64) {
        #pragma unroll
        for (int j = 0; j < 4; ++j) {
            int ci = wid * 4 + j;
            int row = ci * 8 + srow;
            gload16(A  + (size_t)(m0 + row) * K + k0 + scol, &As[ci * 8][0]);
            gload16(Bt + (size_t)(n0 + row) * K + k0 + scol, &Bs[ci * 8][0]);
        }
        __syncthreads();
        #pragma unroll
        for (int ks = 0; ks < 2; ++ks) {
            short8 af[4], bfr[4];
            #pragma unroll
            for (int m = 0; m < 4; ++m)
                af[m] = *(const short8*)&As[wr * 64 + m * 16 + lr][ks * 32 + g * 8];
            #pragma unroll
            for (int n = 0; n < 4; ++n)
                bfr[n] = *(const short8*)&Bs[wc * 64 + n * 16 + lr][ks * 32 + g * 8];
            #pragma unroll
            for (int m = 0; m < 4; ++m)
                #pragma unroll
                for (int n = 0; n < 4; ++n)
                    acc[m][n] = __builtin_amdgcn_mfma_f32_16x16x32_bf16(
                        af[m], bfr[n], acc[m][n], 0, 0, 0);
        }
        __syncthreads();
    }

    #pragma unroll
    for (int n = 0; n < 4; ++n) {
        int coln = n0 + wc * 64 + n * 16 + lr;
        float bv = bias[coln];
        float sc = (coln < qcols) ? 0.125f : 1.0f;
        #pragma unroll
        for (int m = 0; m < 4; ++m) {
            int rowb = m0 + wr * 64 + m * 16 + g * 4;
            #pragma unroll
            for (int r = 0; r < 4; ++r) {
                float v = (acc[m][n][r] + bv) * sc;
                if (BF16OUT)
                    ((unsigned short*)Cout)[(size_t)(rowb + r) * N + coln] = f2bf(v);
                else
                    ((float*)Cout)[(size_t)(rowb + r) * N + coln] = v;
            }
        }
    }
}

// ---------------------------------------------------------------------------
// Flash attention, swapped-QK^T (S^T = K·Q^T), in-register softmax.
// 512 threads = 8 waves, block owns 128 q-rows of one (b,h), KV tile 64.
// LDS: XOR-swizzled K and V^T tiles, double-buffered, global_load_lds staged
// with pre-swizzled per-lane global source (linear LDS dest).
//
// 16x16x32 layouts (verified empirically rounds 1-2):
//   A: lane -> row l&15, k = (l>>4)*8+j     B: col l&15, k = (l>>4)*8+j
//   C/D: col l&15, row (l>>4)*4+r
// Swapped: C col = q (lane-scalar softmax state), row = key.
// PV: O^T[d][q] = sum_k V^T[d][k] * P^T[k][q]  (A=V^T from LDS, B=P^T from regs)
// ---------------------------------------------------------------------------
__global__ __launch_bounds__(512)
void attn_mfma(const unsigned short* __restrict__ qkvb,
               const unsigned short* __restrict__ vtb,
               unsigned short* __restrict__ outb) {
    const int qb = blockIdx.x, h = blockIdx.y, b = blockIdx.z;
    const int tid = threadIdx.x;
    const int wid = tid >> 6, lane = tid & 63;
    const int lr = lane & 15, g = lane >> 4;
    const int q0 = qb * 128;
    const size_t rs = 3 * Cc;
    const int rm7 = lr & 7;

    __shared__ __align__(16) unsigned short Ks[2][64 * 64];
    __shared__ __align__(16) unsigned short Vs[2][64 * 64];

    const unsigned short* qkvbase = qkvb + (size_t)b * Tt * rs;
    const unsigned short* vbase   = vtb + (size_t)((b * Hh + h) * Dd) * Tt;

    const int myq = q0 + wid * 16 + lr;

    // Q B-frag (0.125 scale already folded in by the QKV GEMM)
    short8 qf0, qf1;
    {
        const unsigned short* qp = qkvbase + (size_t)myq * rs + h * Dd;
        qf0 = *(const short8*)(qp + g * 8);
        qf1 = *(const short8*)(qp + 32 + g * 8);
    }

    // staging: lane covers LDS row srow, phys slot lane&7; its content is
    // logical slot (lane&7)^(srow&7)  (XOR-swizzle, involution)
    const int srow = wid * 8 + (lane >> 3);
    const int slog = (lane & 7) ^ (srow & 7);
    const unsigned short* ksrc0 = qkvbase + (size_t)srow * rs + Cc + h * Dd + slog * 8;
    const unsigned short* vsrc0 = vbase + (size_t)srow * Tt + slog * 8;

    f32x4 o[4];
    #pragma unroll
    for (int dt = 0; dt < 4; ++dt) o[dt] = (f32x4){0.f, 0.f, 0.f, 0.f};
    float m_r = -1e30f, l_r = 0.f;

    const int ntiles = 2 * qb + 2;

    auto stage = [&](int bufi, int t) {
        gload16(ksrc0 + (size_t)t * 64 * rs, &Ks[bufi][wid * 512]);
        gload16(vsrc0 + t * 64,              &Vs[bufi][wid * 512]);
    };

    stage(0, 0);
    __syncthreads();
    int cur = 0;

    const int laneA = lr + ((g & 1) << 5);   // src lane for P-relayout, g_src=2*(g&1)
    const int laneB = laneA + 16;
    const int asel  = g >> 1;

    for (int kbt = 0; kbt < ntiles; ++kbt) {
        if (kbt + 1 < ntiles) stage(cur ^ 1, kbt + 1);

        if (kbt * 64 <= q0 + wid * 16 + 15) {
            const unsigned short* Kc = &Ks[cur][0];
            const unsigned short* Vc = &Vs[cur][0];

            // ---- S^T = K Q^T (16 keys x 16 q per mfma, 4 key-tiles) ----
            f32x4 st[4];
            #pragma unroll
            for (int kt = 0; kt < 4; ++kt) {
                int row = kt * 16 + lr;
                int off0 = row * 64 + (g ^ rm7) * 8;          // ks=0: slot g
                short8 kf0 = *(const short8*)&Kc[off0];
                short8 kf1 = *(const short8*)&Kc[off0 ^ 32];  // ks=1: slot g^4 -> +/-32 shorts
                f32x4 a = (f32x4){0.f, 0.f, 0.f, 0.f};
                a = __builtin_amdgcn_mfma_f32_16x16x32_bf16(kf0, qf0, a, 0, 0, 0);
                a = __builtin_amdgcn_mfma_f32_16x16x32_bf16(kf1, qf1, a, 0, 0, 0);
                st[kt] = a;
            }

            // ---- causal mask (diagonal band only) ----
            if (kbt * 64 + 63 > q0 + wid * 16) {
                #pragma unroll
                for (int kt = 0; kt < 4; ++kt)
                    #pragma unroll
                    for (int r = 0; r < 4; ++r)
                        if (kbt * 64 + kt * 16 + g * 4 + r > myq) st[kt][r] = -1e30f;
            }

            // ---- online softmax: all state is lane-scalar (col = q) ----
            float tmax = -1e30f;
            #pragma unroll
            for (int kt = 0; kt < 4; ++kt)
                #pragma unroll
                for (int r = 0; r < 4; ++r) tmax = fmaxf(tmax, st[kt][r]);
            tmax = fmaxf(tmax, __shfl_xor(tmax, 16));
            tmax = fmaxf(tmax, __shfl_xor(tmax, 32));
            float mnew = fmaxf(m_r, tmax);
            float corr = __expf(m_r - mnew);
            float psum = 0.f;
            #pragma unroll
            for (int kt = 0; kt < 4; ++kt)
                #pragma unroll
                for (int r = 0; r < 4; ++r) {
                    float p = __expf(st[kt][r] - mnew);
                    st[kt][r] = p;
                    psum += p;
                }
            psum += __shfl_xor(psum, 16);
            psum += __shfl_xor(psum, 32);
            l_r = l_r * corr + psum;
            m_r = mnew;
            #pragma unroll
            for (int dt = 0; dt < 4; ++dt)
                #pragma unroll
                for (int r = 0; r < 4; ++r) o[dt][r] *= corr;

            // ---- P^T -> PV B-frags, fully in-register (cvt_pk + shfl) ----
            // lane holds P^T[key=kt*16+g*4+r][q]; B-frag ks needs keys 32ks+g*8+j.
            // key k lives at src lane (q | ((k%16)>>2)<<4), word u[k>>4][(k>>1)&1].
            unsigned up[4][2];
            #pragma unroll
            for (int kt = 0; kt < 4; ++kt) {
                asm("v_cvt_pk_bf16_f32 %0, %1, %2"
                    : "=v"(up[kt][0]) : "v"(st[kt][0]), "v"(st[kt][1]));
                asm("v_cvt_pk_bf16_f32 %0, %1, %2"
                    : "=v"(up[kt][1]) : "v"(st[kt][2]), "v"(st[kt][3]));
            }
            #pragma unroll
            for (int ks = 0; ks < 2; ++ks) {
                unsigned wa0 = __shfl(up[2 * ks][0],     laneA);
                unsigned wb0 = __shfl(up[2 * ks + 1][0], laneA);
                unsigned wa1 = __shfl(up[2 * ks][1],     laneA);
                unsigned wb1 = __shfl(up[2 * ks + 1][1], laneA);
                unsigned wa2 = __shfl(up[2 * ks][0],     laneB);
                unsigned wb2 = __shfl(up[2 * ks + 1][0], laneB);
                unsigned wa3 = __shfl(up[2 * ks][1],     laneB);
                unsigned wb3 = __shfl(up[2 * ks + 1][1], laneB);
                union { unsigned w[4]; short8 v; } pb;
                pb.w[0] = asel ? wb0 : wa0;
                pb.w[1] = asel ? wb1 : wa1;
                pb.w[2] = asel ? wb2 : wa2;
                pb.w[3] = asel ? wb3 : wa3;
                #pragma unroll
                for (int dt = 0; dt < 4; ++dt) {
                    int row = dt * 16 + lr;
                    int off = row * 64 + (((ks << 2) | g) ^ rm7) * 8;
                    short8 vf = *(const short8*)&Vc[off];
                    o[dt] = __builtin_amdgcn_mfma_f32_16x16x32_bf16(vf, pb.v, o[dt], 0, 0, 0);
                }
            }
        }
        __syncthreads();
        cur ^= 1;
    }

    // ---- epilogue: lane owns col q; o[dt][r] = O^T[dt*16+g*4+r][q] ----
    float inv = 1.f / l_r;
    unsigned short* op = outb + ((size_t)b * Tt + myq) * Cc + h * Dd + g * 4;
    #pragma unroll
    for (int dt = 0; dt < 4; ++dt) {
        u16x4 w;
        #pragma unroll
        for (int r = 0; r < 4; ++r) w[r] = f2bf(o[dt][r] * inv);
        *(u16x4*)(op + dt * 16) = w;
    }
}

// ---------------------------------------------------------------------------
extern "C" void kernel_launch(void* const* d_in, const int* in_sizes, int n_in,
                              void* d_out, int out_size, void* d_ws, size_t ws_size,
                              hipStream_t stream) {
    const float* x    = (const float*)d_in[0];
    const float* Wqkv = (const float*)d_in[1];
    const float* bqkv = (const float*)d_in[2];
    const float* Wout = (const float*)d_in[3];
    const float* bout = (const float*)d_in[4];
    float* out = (float*)d_out;

    const int M = Bb * Tt;          // 8192
    const int N1 = 3 * Cc;          // 2304

    char* p = (char*)d_ws;
    unsigned short* qkvb  = (unsigned short*)p; p += (size_t)M * N1 * 2;
    unsigned short* xb    = (unsigned short*)p; p += (size_t)M * Cc * 2;
    unsigned short* wqkvt = (unsigned short*)p; p += (size_t)N1 * Cc * 2;
    unsigned short* woutt = (unsigned short*)p; p += (size_t)Cc * Cc * 2;
    unsigned short* vtb   = (unsigned short*)p; p += (size_t)Bb * Hh * Dd * Tt * 2;
    unsigned short* attb  = (unsigned short*)p; p += (size_t)M * Cc * 2;

    cvt_bf16<<<dim3((M * Cc / 8 + 255) / 256), dim3(256), 0, stream>>>(x, xb, M * Cc / 8);
    transpose_w<<<dim3(N1 / 64, Cc / 64), dim3(256), 0, stream>>>(Wqkv, wqkvt, Cc, N1);
    transpose_w<<<dim3(Cc / 64, Cc / 64), dim3(256), 0, stream>>>(Wout, woutt, Cc, Cc);

    // qkv = x @ Wqkv + bqkv, Q columns pre-scaled by 0.125 (bf16 out)
    gemm_mfma<true><<<dim3(N1 / 128, M / 128), dim3(256), 0, stream>>>(
        xb, wqkvt, bqkv, qkvb, M, N1, Cc, Cc);

    repack_vt<<<dim3(Tt / 64, Hh, Bb), dim3(256), 0, stream>>>(qkvb, vtb);

    attn_mfma<<<dim3(Tt / 128, Hh, Bb), dim3(512), 0, stream>>>(qkvb, vtb, attb);

    gemm_mfma<false><<<dim3(Cc / 128, M / 128), dim3(256), 0, stream>>>(
        attb, woutt, bout, out, M, Cc, Cc, 0);
}

// Round 6
// 271.107 us; speedup vs baseline: 23.9854x; 1.0436x over previous
//
#include <hip/hip_runtime.h>
#include <math.h>

#define Bb 2
#define Tt 4096
#define Cc 768
#define Hh 12
#define Dd 64

typedef __attribute__((ext_vector_type(8))) short short8;
typedef __attribute__((ext_vector_type(4))) float f32x4;
typedef __attribute__((ext_vector_type(4))) unsigned short u16x4;

static __device__ __forceinline__ unsigned short f2bf(float f) {
    unsigned u = __float_as_uint(f);
    u += 0x7FFF + ((u >> 16) & 1);          // round-to-nearest-even
    return (unsigned short)(u >> 16);
}

static __device__ __forceinline__ float ex2(float x) {
    return __builtin_amdgcn_exp2f(x);
}

static __device__ __forceinline__ void gload16(const void* g, void* l) {
    __builtin_amdgcn_global_load_lds(
        (const __attribute__((address_space(1))) unsigned*)g,
        (__attribute__((address_space(3))) unsigned*)l, 16, 0, 0);
}

// ---------------------------------------------------------------------------
// fp32 -> bf16 elementwise convert (8 elems/thread)
// ---------------------------------------------------------------------------
__global__ __launch_bounds__(256)
void cvt_bf16(const float* __restrict__ in, unsigned short* __restrict__ out, int n8) {
    int i = blockIdx.x * 256 + threadIdx.x;
    if (i >= n8) return;
    float4 a = *(const float4*)(in + (size_t)i * 8);
    float4 b = *(const float4*)(in + (size_t)i * 8 + 4);
    union { short8 v; unsigned short u[8]; } p;
    p.u[0] = f2bf(a.x); p.u[1] = f2bf(a.y); p.u[2] = f2bf(a.z); p.u[3] = f2bf(a.w);
    p.u[4] = f2bf(b.x); p.u[5] = f2bf(b.y); p.u[6] = f2bf(b.z); p.u[7] = f2bf(b.w);
    *(short8*)(out + (size_t)i * 8) = p.v;
}

// ---------------------------------------------------------------------------
// W[K][N] fp32 -> Wt[N][K] bf16 (64x64 LDS tile transpose)
// ---------------------------------------------------------------------------
__global__ __launch_bounds__(256)
void transpose_w(const float* __restrict__ W, unsigned short* __restrict__ Wt,
                 int K, int N) {
    __shared__ __align__(16) unsigned short Tl[64][72];
    int n0 = blockIdx.x * 64, k0 = blockIdx.y * 64;
    int t = threadIdx.x;
    int r = t >> 2, c = (t & 3) * 16;
    const float* wp = W + (size_t)(k0 + r) * N + n0 + c;
    #pragma unroll
    for (int j = 0; j < 16; j += 4) {
        float4 v = *(const float4*)(wp + j);
        Tl[c + j + 0][r] = f2bf(v.x);
        Tl[c + j + 1][r] = f2bf(v.y);
        Tl[c + j + 2][r] = f2bf(v.z);
        Tl[c + j + 3][r] = f2bf(v.w);
    }
    __syncthreads();
    unsigned short* op = Wt + (size_t)(n0 + r) * K + k0 + c;
    *(short8*)op       = *(const short8*)&Tl[r][c];
    *(short8*)(op + 8) = *(const short8*)&Tl[r][c + 8];
}

// ---------------------------------------------------------------------------
// V slice of bf16 qkv -> Vt[b][h][d][t]  (64x64 LDS tile transpose)
// ---------------------------------------------------------------------------
__global__ __launch_bounds__(256)
void repack_vt(const unsigned short* __restrict__ qkvb, unsigned short* __restrict__ vtb) {
    __shared__ __align__(16) unsigned short Tl[64][72];
    int t0 = blockIdx.x * 64, h = blockIdx.y, b = blockIdx.z;
    int t = threadIdx.x;
    int r = t >> 2, c = (t & 3) * 16;
    const unsigned short* vp = qkvb + (size_t)((size_t)b * Tt + t0 + r) * (3 * Cc)
                               + 2 * Cc + h * Dd + c;
    short8 v0 = *(const short8*)vp;
    short8 v1 = *(const short8*)(vp + 8);
    #pragma unroll
    for (int j = 0; j < 8; ++j) {
        Tl[c + j][r]     = ((unsigned short*)&v0)[j];
        Tl[c + 8 + j][r] = ((unsigned short*)&v1)[j];
    }
    __syncthreads();
    unsigned short* op = vtb + ((size_t)((b * Hh + h) * Dd) + r) * Tt + t0 + c;
    *(short8*)op       = *(const short8*)&Tl[r][c];
    *(short8*)(op + 8) = *(const short8*)&Tl[r][c + 8];
}

// ---------------------------------------------------------------------------
// bf16 MFMA GEMM: C[M,N] = (A[M,K] @ Bt[N,K]^T + bias) * (col<qcols ? qscale : 1)
// 128x128 tile, BK=64, 256 threads (4 waves, 2x2), global_load_lds staging.
// ---------------------------------------------------------------------------
template<bool BF16OUT>
__global__ __launch_bounds__(256)
void gemm_mfma(const unsigned short* __restrict__ A, const unsigned short* __restrict__ Bt,
               const float* __restrict__ bias, void* __restrict__ Cout,
               int M, int N, int K, int qcols) {
    __shared__ __align__(16) unsigned short As[128][64];
    __shared__ __align__(16) unsigned short Bs[128][64];
    const int tid = threadIdx.x;
    const int wid = tid >> 6, lane = tid & 63;
    const int lr = lane & 15, g = lane >> 4;
    const int wr = wid >> 1, wc = wid & 1;
    const int m0 = blockIdx.y * 128, n0 = blockIdx.x * 128;
    const int srow = lane >> 3;
    const int scol = (lane & 7) * 8;

    f32x4 acc[4][4] = {};

    for (int k0 = 0; k0 < K; k0 += 64) {
        #pragma unroll
        for (int j = 0; j < 4; ++j) {
            int ci = wid * 4 + j;
            int row = ci * 8 + srow;
            gload16(A  + (size_t)(m0 + row) * K + k0 + scol, &As[ci * 8][0]);
            gload16(Bt + (size_t)(n0 + row) * K + k0 + scol, &Bs[ci * 8][0]);
        }
        __syncthreads();
        #pragma unroll
        for (int ks = 0; ks < 2; ++ks) {
            short8 af[4], bfr[4];
            #pragma unroll
            for (int m = 0; m < 4; ++m)
                af[m] = *(const short8*)&As[wr * 64 + m * 16 + lr][ks * 32 + g * 8];
            #pragma unroll
            for (int n = 0; n < 4; ++n)
                bfr[n] = *(const short8*)&Bs[wc * 64 + n * 16 + lr][ks * 32 + g * 8];
            #pragma unroll
            for (int m = 0; m < 4; ++m)
                #pragma unroll
                for (int n = 0; n < 4; ++n)
                    acc[m][n] = __builtin_amdgcn_mfma_f32_16x16x32_bf16(
                        af[m], bfr[n], acc[m][n], 0, 0, 0);
        }
        __syncthreads();
    }

    // qscale = 0.125 * log2(e): QK^T scores land directly in log2 domain.
    const float qscale = 0.125f * 1.44269504088896340736f;
    #pragma unroll
    for (int n = 0; n < 4; ++n) {
        int coln = n0 + wc * 64 + n * 16 + lr;
        float bv = bias[coln];
        float sc = (coln < qcols) ? qscale : 1.0f;
        #pragma unroll
        for (int m = 0; m < 4; ++m) {
            int rowb = m0 + wr * 64 + m * 16 + g * 4;
            #pragma unroll
            for (int r = 0; r < 4; ++r) {
                float v = (acc[m][n][r] + bv) * sc;
                if (BF16OUT)
                    ((unsigned short*)Cout)[(size_t)(rowb + r) * N + coln] = f2bf(v);
                else
                    ((float*)Cout)[(size_t)(rowb + r) * N + coln] = v;
            }
        }
    }
}

// ---------------------------------------------------------------------------
// Flash attention, swapped-QK^T (S^T = K·Q^T), in-register softmax (log2
// domain), defer-max, longest-first block order, setprio around MFMA.
// 512 threads = 8 waves, block owns 128 q-rows of one (b,h), KV tile 64.
// ---------------------------------------------------------------------------
__global__ __launch_bounds__(512)
void attn_mfma(const unsigned short* __restrict__ qkvb,
               const unsigned short* __restrict__ vtb,
               unsigned short* __restrict__ outb) {
    const int qb = (int)(gridDim.x - 1) - blockIdx.x;   // longest-first
    const int h = blockIdx.y, b = blockIdx.z;
    const int tid = threadIdx.x;
    const int wid = tid >> 6, lane = tid & 63;
    const int lr = lane & 15, g = lane >> 4;
    const int q0 = qb * 128;
    const size_t rs = 3 * Cc;
    const int rm7 = lr & 7;

    __shared__ __align__(16) unsigned short Ks[2][64 * 64];
    __shared__ __align__(16) unsigned short Vs[2][64 * 64];

    const unsigned short* qkvbase = qkvb + (size_t)b * Tt * rs;
    const unsigned short* vbase   = vtb + (size_t)((b * Hh + h) * Dd) * Tt;

    const int myq = q0 + wid * 16 + lr;

    // Q B-frag (0.125*log2e scale folded in by the QKV GEMM)
    short8 qf0, qf1;
    {
        const unsigned short* qp = qkvbase + (size_t)myq * rs + h * Dd;
        qf0 = *(const short8*)(qp + g * 8);
        qf1 = *(const short8*)(qp + 32 + g * 8);
    }

    // staging: lane covers LDS row srow, phys slot lane&7; content is logical
    // slot (lane&7)^(srow&7)  (XOR-swizzle involution, rule #21)
    const int srow = wid * 8 + (lane >> 3);
    const int slog = (lane & 7) ^ (srow & 7);
    const unsigned short* ksrc0 = qkvbase + (size_t)srow * rs + Cc + h * Dd + slog * 8;
    const unsigned short* vsrc0 = vbase + (size_t)srow * Tt + slog * 8;

    f32x4 o[4];
    #pragma unroll
    for (int dt = 0; dt < 4; ++dt) o[dt] = (f32x4){0.f, 0.f, 0.f, 0.f};
    float m_r = -1e30f, l_r = 0.f;

    const int ntiles = 2 * qb + 2;

    auto stage = [&](int bufi, int t) {
        gload16(ksrc0 + (size_t)t * 64 * rs, &Ks[bufi][wid * 512]);
        gload16(vsrc0 + t * 64,              &Vs[bufi][wid * 512]);
    };

    stage(0, 0);
    __syncthreads();
    int cur = 0;

    const int laneA = lr + ((g & 1) << 5);   // src lane for P-relayout
    const int laneB = laneA + 16;
    const int asel  = g >> 1;

    for (int kbt = 0; kbt < ntiles; ++kbt) {
        if (kbt + 1 < ntiles) stage(cur ^ 1, kbt + 1);

        if (kbt * 64 <= q0 + wid * 16 + 15) {
            const unsigned short* Kc = &Ks[cur][0];
            const unsigned short* Vc = &Vs[cur][0];

            // ---- S^T = K Q^T (scores in log2 domain) ----
            f32x4 st[4];
            __builtin_amdgcn_s_setprio(1);
            #pragma unroll
            for (int kt = 0; kt < 4; ++kt) {
                int row = kt * 16 + lr;
                int off0 = row * 64 + (g ^ rm7) * 8;
                short8 kf0 = *(const short8*)&Kc[off0];
                short8 kf1 = *(const short8*)&Kc[off0 ^ 32];
                f32x4 a = (f32x4){0.f, 0.f, 0.f, 0.f};
                a = __builtin_amdgcn_mfma_f32_16x16x32_bf16(kf0, qf0, a, 0, 0, 0);
                a = __builtin_amdgcn_mfma_f32_16x16x32_bf16(kf1, qf1, a, 0, 0, 0);
                st[kt] = a;
            }
            __builtin_amdgcn_s_setprio(0);

            // ---- causal mask (diagonal band only) ----
            if (kbt * 64 + 63 > q0 + wid * 16) {
                #pragma unroll
                for (int kt = 0; kt < 4; ++kt)
                    #pragma unroll
                    for (int r = 0; r < 4; ++r)
                        if (kbt * 64 + kt * 16 + g * 4 + r > myq) st[kt][r] = -1e30f;
            }

            // ---- online softmax, log2 domain, defer-max (T13, THR=8) ----
            float tmax = -1e30f;
            #pragma unroll
            for (int kt = 0; kt < 4; ++kt)
                #pragma unroll
                for (int r = 0; r < 4; ++r) tmax = fmaxf(tmax, st[kt][r]);
            tmax = fmaxf(tmax, __shfl_xor(tmax, 16));
            tmax = fmaxf(tmax, __shfl_xor(tmax, 32));
            if (!__all(tmax - m_r <= 8.0f)) {
                float mnew = fmaxf(m_r, tmax);
                float corr = ex2(m_r - mnew);
                l_r *= corr;
                #pragma unroll
                for (int dt = 0; dt < 4; ++dt)
                    #pragma unroll
                    for (int r = 0; r < 4; ++r) o[dt][r] *= corr;
                m_r = mnew;
            }
            float psum = 0.f;
            #pragma unroll
            for (int kt = 0; kt < 4; ++kt)
                #pragma unroll
                for (int r = 0; r < 4; ++r) {
                    float p = ex2(st[kt][r] - m_r);
                    st[kt][r] = p;
                    psum += p;
                }
            psum += __shfl_xor(psum, 16);
            psum += __shfl_xor(psum, 32);
            l_r += psum;

            // ---- P^T -> PV B-frags in-register (cvt_pk + shfl) ----
            unsigned up[4][2];
            #pragma unroll
            for (int kt = 0; kt < 4; ++kt) {
                asm("v_cvt_pk_bf16_f32 %0, %1, %2"
                    : "=v"(up[kt][0]) : "v"(st[kt][0]), "v"(st[kt][1]));
                asm("v_cvt_pk_bf16_f32 %0, %1, %2"
                    : "=v"(up[kt][1]) : "v"(st[kt][2]), "v"(st[kt][3]));
            }
            #pragma unroll
            for (int ks = 0; ks < 2; ++ks) {
                unsigned wa0 = __shfl(up[2 * ks][0],     laneA);
                unsigned wb0 = __shfl(up[2 * ks + 1][0], laneA);
                unsigned wa1 = __shfl(up[2 * ks][1],     laneA);
                unsigned wb1 = __shfl(up[2 * ks + 1][1], laneA);
                unsigned wa2 = __shfl(up[2 * ks][0],     laneB);
                unsigned wb2 = __shfl(up[2 * ks + 1][0], laneB);
                unsigned wa3 = __shfl(up[2 * ks][1],     laneB);
                unsigned wb3 = __shfl(up[2 * ks + 1][1], laneB);
                union { unsigned w[4]; short8 v; } pb;
                pb.w[0] = asel ? wb0 : wa0;
                pb.w[1] = asel ? wb1 : wa1;
                pb.w[2] = asel ? wb2 : wa2;
                pb.w[3] = asel ? wb3 : wa3;
                __builtin_amdgcn_s_setprio(1);
                #pragma unroll
                for (int dt = 0; dt < 4; ++dt) {
                    int row = dt * 16 + lr;
                    int off = row * 64 + (((ks << 2) | g) ^ rm7) * 8;
                    short8 vf = *(const short8*)&Vc[off];
                    o[dt] = __builtin_amdgcn_mfma_f32_16x16x32_bf16(vf, pb.v, o[dt], 0, 0, 0);
                }
                __builtin_amdgcn_s_setprio(0);
            }
        }
        __syncthreads();
        cur ^= 1;
    }

    // ---- epilogue: lane owns col q; o[dt][r] = O^T[dt*16+g*4+r][q] ----
    float inv = 1.f / l_r;
    unsigned short* op = outb + ((size_t)b * Tt + myq) * Cc + h * Dd + g * 4;
    #pragma unroll
    for (int dt = 0; dt < 4; ++dt) {
        u16x4 w;
        #pragma unroll
        for (int r = 0; r < 4; ++r) w[r] = f2bf(o[dt][r] * inv);
        *(u16x4*)(op + dt * 16) = w;
    }
}

// ---------------------------------------------------------------------------
extern "C" void kernel_launch(void* const* d_in, const int* in_sizes, int n_in,
                              void* d_out, int out_size, void* d_ws, size_t ws_size,
                              hipStream_t stream) {
    const float* x    = (const float*)d_in[0];
    const float* Wqkv = (const float*)d_in[1];
    const float* bqkv = (const float*)d_in[2];
    const float* Wout = (const float*)d_in[3];
    const float* bout = (const float*)d_in[4];
    float* out = (float*)d_out;

    const int M = Bb * Tt;          // 8192
    const int N1 = 3 * Cc;          // 2304

    char* p = (char*)d_ws;
    unsigned short* qkvb  = (unsigned short*)p; p += (size_t)M * N1 * 2;
    unsigned short* xb    = (unsigned short*)p; p += (size_t)M * Cc * 2;
    unsigned short* wqkvt = (unsigned short*)p; p += (size_t)N1 * Cc * 2;
    unsigned short* woutt = (unsigned short*)p; p += (size_t)Cc * Cc * 2;
    unsigned short* vtb   = (unsigned short*)p; p += (size_t)Bb * Hh * Dd * Tt * 2;
    unsigned short* attb  = (unsigned short*)p; p += (size_t)M * Cc * 2;

    cvt_bf16<<<dim3((M * Cc / 8 + 255) / 256), dim3(256), 0, stream>>>(x, xb, M * Cc / 8);
    transpose_w<<<dim3(N1 / 64, Cc / 64), dim3(256), 0, stream>>>(Wqkv, wqkvt, Cc, N1);
    transpose_w<<<dim3(Cc / 64, Cc / 64), dim3(256), 0, stream>>>(Wout, woutt, Cc, Cc);

    // qkv = x @ Wqkv + bqkv, Q columns pre-scaled by 0.125*log2(e) (bf16 out)
    gemm_mfma<true><<<dim3(N1 / 128, M / 128), dim3(256), 0, stream>>>(
        xb, wqkvt, bqkv, qkvb, M, N1, Cc, Cc);

    repack_vt<<<dim3(Tt / 64, Hh, Bb), dim3(256), 0, stream>>>(qkvb, vtb);

    attn_mfma<<<dim3(Tt / 128, Hh, Bb), dim3(512), 0, stream>>>(qkvb, vtb, attb);

    gemm_mfma<false><<<dim3(Cc / 128, M / 128), dim3(256), 0, stream>>>(
        attb, woutt, bout, out, M, Cc, Cc, 0);
}